// Round 1
// baseline (6094.492 us; speedup 1.0000x reference)
//
#include <hip/hip_runtime.h>

#define N_NODES  50000
#define IN_F     128
#define OUT_F    128
#define N_REL    8
#define N_BASES  4
#define N_EDGES  800000

// ws[r,i,o] = sum_b w_comp[r,b] * weight[b,i,o]
__global__ __launch_bounds__(256) void compute_ws_kernel(
    const float* __restrict__ weight,
    const float* __restrict__ w_comp,
    float* __restrict__ ws)
{
    int idx = blockIdx.x * 256 + threadIdx.x;            // over R*IN*OUT
    if (idx >= N_REL * IN_F * OUT_F) return;
    int io = idx & (IN_F * OUT_F - 1);                   // 16384 = 2^14
    int r  = idx >> 14;
    float acc = 0.f;
#pragma unroll
    for (int b = 0; b < N_BASES; ++b)
        acc += w_comp[r * N_BASES + b] * weight[b * (IN_F * OUT_F) + io];
    ws[idx] = acc;
}

// One edge per 64-lane wave; each lane handles 2 consecutive floats.
// agg[dst] += x[src]; deg[dst] += 1
__global__ __launch_bounds__(256) void scatter_kernel(
    const float* __restrict__ x,
    const int* __restrict__ src,
    const int* __restrict__ dst,
    float* __restrict__ agg,
    float* __restrict__ deg)
{
    int lane = threadIdx.x & 63;
    int waveInBlock = threadIdx.x >> 6;                  // 0..3
    int stride = gridDim.x * 4;
    for (int e = blockIdx.x * 4 + waveInBlock; e < N_EDGES; e += stride) {
        int s = src[e];
        int d = dst[e];
        const float2 v = *(const float2*)(x + (size_t)s * IN_F + lane * 2);
        float* a = agg + (size_t)d * OUT_F + lane * 2;
        atomicAdd(a,     v.x);
        atomicAdd(a + 1, v.y);
        if (lane == 0) atomicAdd(deg + d, 1.0f);
    }
}

// out[n, :] += (agg[n, :] / max(deg[n],1)) @ wsr   for one relation
// Block: 256 threads -> 32 rows x 128 cols; thread = 4 rows x 4 cols.
__global__ __launch_bounds__(256) void gemm_acc_kernel(
    const float* __restrict__ agg,
    const float* __restrict__ deg,
    const float* __restrict__ wsr,
    float* __restrict__ out)
{
    int t  = threadIdx.x;
    int oq = t & 31;              // column group: cols 4*oq .. 4*oq+3
    int rq = t >> 5;              // 0..7
    int row0 = blockIdx.x * 32 + rq * 4;

    // clamp rows for safe reads; writes are guarded
    int r0 = min(row0 + 0, N_NODES - 1);
    int r1 = min(row0 + 1, N_NODES - 1);
    int r2 = min(row0 + 2, N_NODES - 1);
    int r3 = min(row0 + 3, N_NODES - 1);
    const float* A0 = agg + (size_t)r0 * IN_F;
    const float* A1 = agg + (size_t)r1 * IN_F;
    const float* A2 = agg + (size_t)r2 * IN_F;
    const float* A3 = agg + (size_t)r3 * IN_F;

    float acc0[4] = {0,0,0,0}, acc1[4] = {0,0,0,0};
    float acc2[4] = {0,0,0,0}, acc3[4] = {0,0,0,0};

#pragma unroll 4
    for (int k = 0; k < IN_F; ++k) {
        const float4 w = *(const float4*)(wsr + (size_t)k * OUT_F + oq * 4);
        const float a0 = A0[k], a1 = A1[k], a2 = A2[k], a3 = A3[k];
        acc0[0] = fmaf(a0, w.x, acc0[0]); acc0[1] = fmaf(a0, w.y, acc0[1]);
        acc0[2] = fmaf(a0, w.z, acc0[2]); acc0[3] = fmaf(a0, w.w, acc0[3]);
        acc1[0] = fmaf(a1, w.x, acc1[0]); acc1[1] = fmaf(a1, w.y, acc1[1]);
        acc1[2] = fmaf(a1, w.z, acc1[2]); acc1[3] = fmaf(a1, w.w, acc1[3]);
        acc2[0] = fmaf(a2, w.x, acc2[0]); acc2[1] = fmaf(a2, w.y, acc2[1]);
        acc2[2] = fmaf(a2, w.z, acc2[2]); acc2[3] = fmaf(a2, w.w, acc2[3]);
        acc3[0] = fmaf(a3, w.x, acc3[0]); acc3[1] = fmaf(a3, w.y, acc3[1]);
        acc3[2] = fmaf(a3, w.z, acc3[2]); acc3[3] = fmaf(a3, w.w, acc3[3]);
    }

    const float i0 = 1.0f / fmaxf(deg[r0], 1.0f);
    const float i1 = 1.0f / fmaxf(deg[r1], 1.0f);
    const float i2 = 1.0f / fmaxf(deg[r2], 1.0f);
    const float i3 = 1.0f / fmaxf(deg[r3], 1.0f);

    float* o0 = out + (size_t)(row0 + 0) * OUT_F + oq * 4;
    float* o1 = out + (size_t)(row0 + 1) * OUT_F + oq * 4;
    float* o2 = out + (size_t)(row0 + 2) * OUT_F + oq * 4;
    float* o3 = out + (size_t)(row0 + 3) * OUT_F + oq * 4;

    if (row0 + 0 < N_NODES) { for (int j = 0; j < 4; ++j) o0[j] += acc0[j] * i0; }
    if (row0 + 1 < N_NODES) { for (int j = 0; j < 4; ++j) o1[j] += acc1[j] * i1; }
    if (row0 + 2 < N_NODES) { for (int j = 0; j < 4; ++j) o2[j] += acc2[j] * i2; }
    if (row0 + 3 < N_NODES) { for (int j = 0; j < 4; ++j) o3[j] += acc3[j] * i3; }
}

__global__ __launch_bounds__(256) void bias_relu_kernel(
    float* __restrict__ out, const float* __restrict__ bias)
{
    int idx = blockIdx.x * 256 + threadIdx.x;            // over N*OUT/4
    if (idx >= N_NODES * OUT_F / 4) return;
    float4 v = *((float4*)out + idx);
    int o = (idx * 4) & (OUT_F - 1);
    const float4 b = *(const float4*)(bias + o);
    v.x = fmaxf(v.x + b.x, 0.f);
    v.y = fmaxf(v.y + b.y, 0.f);
    v.z = fmaxf(v.z + b.z, 0.f);
    v.w = fmaxf(v.w + b.w, 0.f);
    *((float4*)out + idx) = v;
}

extern "C" void kernel_launch(void* const* d_in, const int* in_sizes, int n_in,
                              void* d_out, int out_size, void* d_ws, size_t ws_size,
                              hipStream_t stream) {
    const float* x      = (const float*)d_in[0];
    const float* weight = (const float*)d_in[1];
    const float* w_comp = (const float*)d_in[2];
    const float* h_bias = (const float*)d_in[3];
    const int*   src    = (const int*)d_in[4];
    const int*   dst    = (const int*)d_in[5];
    float* out = (float*)d_out;

    char* wsb = (char*)d_ws;
    float* ws_r = (float*)wsb;                               // R*IN*OUT  = 512 KB
    float* agg  = (float*)(wsb + 524288);                    // N*OUT f32 = 25.6 MB
    float* deg  = (float*)(wsb + 524288 + 25600000);         // N f32     = 200 KB

    hipMemsetAsync(d_out, 0, (size_t)N_NODES * OUT_F * sizeof(float), stream);
    compute_ws_kernel<<<(N_REL * IN_F * OUT_F + 255) / 256, 256, 0, stream>>>(
        weight, w_comp, ws_r);

    for (int r = 0; r < N_REL; ++r) {
        hipMemsetAsync(agg, 0, (size_t)N_NODES * OUT_F * sizeof(float), stream);
        hipMemsetAsync(deg, 0, (size_t)N_NODES * sizeof(float), stream);
        scatter_kernel<<<4096, 256, 0, stream>>>(
            x, src + (size_t)r * N_EDGES, dst + (size_t)r * N_EDGES, agg, deg);
        gemm_acc_kernel<<<(N_NODES + 31) / 32, 256, 0, stream>>>(
            agg, deg, ws_r + (size_t)r * IN_F * OUT_F, out);
    }

    bias_relu_kernel<<<(N_NODES * OUT_F / 4 + 255) / 256, 256, 0, stream>>>(
        out, h_bias);
}

// Round 2
// 1325.696 us; speedup vs baseline: 4.5972x; 4.5972x over previous
//
#include <hip/hip_runtime.h>

#define N_NODES  50000
#define IN_F     128
#define OUT_F    128
#define N_REL    8
#define N_BASES  4
#define N_EDGES  800000
#define BUCKET_CAP 64

// ws[r,i,o] = sum_b w_comp[r,b] * weight[b,i,o]
__global__ __launch_bounds__(256) void compute_ws_kernel(
    const float* __restrict__ weight,
    const float* __restrict__ w_comp,
    float* __restrict__ ws)
{
    int idx = blockIdx.x * 256 + threadIdx.x;            // over R*IN*OUT
    if (idx >= N_REL * IN_F * OUT_F) return;
    int io = idx & (IN_F * OUT_F - 1);                   // 16384 = 2^14
    int r  = idx >> 14;
    float acc = 0.f;
#pragma unroll
    for (int b = 0; b < N_BASES; ++b)
        acc += w_comp[r * N_BASES + b] * weight[b * (IN_F * OUT_F) + io];
    ws[idx] = acc;
}

// Per edge: count dst degree and drop src id into dst's bucket.
__global__ __launch_bounds__(256) void bucket_fill_kernel(
    const int* __restrict__ src,
    const int* __restrict__ dst,
    int* __restrict__ cnt,
    unsigned short* __restrict__ bucket)
{
    int e = blockIdx.x * 256 + threadIdx.x;
    if (e >= N_EDGES) return;
    int d = dst[e];
    int pos = atomicAdd(&cnt[d], 1);
    if (pos < BUCKET_CAP)
        bucket[d * BUCKET_CAP + pos] = (unsigned short)src[e];
}

// One wave per node: load its src list (coalesced), broadcast via shfl,
// accumulate x rows in registers, write the MEAN once. No float atomics.
__global__ __launch_bounds__(256) void gather_mean_kernel(
    const float* __restrict__ x,
    const int* __restrict__ cnt,
    const unsigned short* __restrict__ bucket,
    float* __restrict__ agg)
{
    int wave = (blockIdx.x * 256 + threadIdx.x) >> 6;
    int lane = threadIdx.x & 63;
    if (wave >= N_NODES) return;
    int c  = cnt[wave];
    int cc = min(c, BUCKET_CAP);
    int sid = (lane < cc) ? (int)bucket[wave * BUCKET_CAP + lane] : 0;

    float ax = 0.f, ay = 0.f, bx = 0.f, by = 0.f;
    int e = 0;
    for (; e + 2 <= cc; e += 2) {
        int s0 = __shfl(sid, e);
        int s1 = __shfl(sid, e + 1);
        const float2 v0 = *(const float2*)(x + (size_t)s0 * IN_F + lane * 2);
        const float2 v1 = *(const float2*)(x + (size_t)s1 * IN_F + lane * 2);
        ax += v0.x; ay += v0.y;
        bx += v1.x; by += v1.y;
    }
    if (e < cc) {
        int s0 = __shfl(sid, e);
        const float2 v0 = *(const float2*)(x + (size_t)s0 * IN_F + lane * 2);
        ax += v0.x; ay += v0.y;
    }
    const float inv = 1.0f / fmaxf((float)c, 1.0f);
    float2 r;
    r.x = (ax + bx) * inv;
    r.y = (ay + by) * inv;
    *(float2*)(agg + (size_t)wave * IN_F + lane * 2) = r;
}

// out[n,:] (first? = : +=) mean[n,:] @ wsr ; last relation fuses bias+relu.
// Block: 256 threads -> 32 rows x 128 cols; thread = 4 rows x 4 cols.
__global__ __launch_bounds__(256) void gemm_acc_kernel(
    const float* __restrict__ agg,
    const float* __restrict__ wsr,
    float* __restrict__ out,
    const float* __restrict__ bias,
    int first, int last)
{
    int t  = threadIdx.x;
    int oq = t & 31;              // column group: cols 4*oq .. 4*oq+3
    int rq = t >> 5;              // 0..7
    int row0 = blockIdx.x * 32 + rq * 4;

    int r0 = min(row0 + 0, N_NODES - 1);
    int r1 = min(row0 + 1, N_NODES - 1);
    int r2 = min(row0 + 2, N_NODES - 1);
    int r3 = min(row0 + 3, N_NODES - 1);
    const float* A0 = agg + (size_t)r0 * IN_F;
    const float* A1 = agg + (size_t)r1 * IN_F;
    const float* A2 = agg + (size_t)r2 * IN_F;
    const float* A3 = agg + (size_t)r3 * IN_F;

    float acc0[4] = {0,0,0,0}, acc1[4] = {0,0,0,0};
    float acc2[4] = {0,0,0,0}, acc3[4] = {0,0,0,0};

#pragma unroll 4
    for (int k = 0; k < IN_F; ++k) {
        const float4 w = *(const float4*)(wsr + (size_t)k * OUT_F + oq * 4);
        const float a0 = A0[k], a1 = A1[k], a2 = A2[k], a3 = A3[k];
        acc0[0] = fmaf(a0, w.x, acc0[0]); acc0[1] = fmaf(a0, w.y, acc0[1]);
        acc0[2] = fmaf(a0, w.z, acc0[2]); acc0[3] = fmaf(a0, w.w, acc0[3]);
        acc1[0] = fmaf(a1, w.x, acc1[0]); acc1[1] = fmaf(a1, w.y, acc1[1]);
        acc1[2] = fmaf(a1, w.z, acc1[2]); acc1[3] = fmaf(a1, w.w, acc1[3]);
        acc2[0] = fmaf(a2, w.x, acc2[0]); acc2[1] = fmaf(a2, w.y, acc2[1]);
        acc2[2] = fmaf(a2, w.z, acc2[2]); acc2[3] = fmaf(a2, w.w, acc2[3]);
        acc3[0] = fmaf(a3, w.x, acc3[0]); acc3[1] = fmaf(a3, w.y, acc3[1]);
        acc3[2] = fmaf(a3, w.z, acc3[2]); acc3[3] = fmaf(a3, w.w, acc3[3]);
    }

    const float4 b = *(const float4*)(bias + oq * 4);

#define EPILOG(ACC, ROW, RP)                                                  \
    if ((ROW) < N_NODES) {                                                    \
        float* o = out + (size_t)(ROW) * OUT_F + oq * 4;                      \
        float4 v;                                                             \
        v.x = ACC[0]; v.y = ACC[1]; v.z = ACC[2]; v.w = ACC[3];               \
        if (!first) { float4 p = *(float4*)o;                                 \
            v.x += p.x; v.y += p.y; v.z += p.z; v.w += p.w; }                 \
        if (last) {                                                           \
            v.x = fmaxf(v.x + b.x, 0.f); v.y = fmaxf(v.y + b.y, 0.f);         \
            v.z = fmaxf(v.z + b.z, 0.f); v.w = fmaxf(v.w + b.w, 0.f); }      \
        *(float4*)o = v;                                                      \
    }

    EPILOG(acc0, row0 + 0, r0)
    EPILOG(acc1, row0 + 1, r1)
    EPILOG(acc2, row0 + 2, r2)
    EPILOG(acc3, row0 + 3, r3)
#undef EPILOG
}

extern "C" void kernel_launch(void* const* d_in, const int* in_sizes, int n_in,
                              void* d_out, int out_size, void* d_ws, size_t ws_size,
                              hipStream_t stream) {
    const float* x      = (const float*)d_in[0];
    const float* weight = (const float*)d_in[1];
    const float* w_comp = (const float*)d_in[2];
    const float* h_bias = (const float*)d_in[3];
    const int*   src    = (const int*)d_in[4];
    const int*   dst    = (const int*)d_in[5];
    float* out = (float*)d_out;

    char* wsb = (char*)d_ws;
    float*          ws_r   = (float*)wsb;                         // 512 KB
    float*          agg    = (float*)(wsb + 524288);              // 25.6 MB
    int*            cnt    = (int*)(wsb + 524288 + 25600000);     // 200 KB
    unsigned short* bucket = (unsigned short*)(wsb + 524288 + 25600000 + 200000); // 6.4 MB

    compute_ws_kernel<<<(N_REL * IN_F * OUT_F + 255) / 256, 256, 0, stream>>>(
        weight, w_comp, ws_r);

    for (int r = 0; r < N_REL; ++r) {
        hipMemsetAsync(cnt, 0, (size_t)N_NODES * sizeof(int), stream);
        bucket_fill_kernel<<<(N_EDGES + 255) / 256, 256, 0, stream>>>(
            src + (size_t)r * N_EDGES, dst + (size_t)r * N_EDGES, cnt, bucket);
        gather_mean_kernel<<<(N_NODES * 64 + 255) / 256, 256, 0, stream>>>(
            x, cnt, bucket, agg);
        gemm_acc_kernel<<<(N_NODES + 31) / 32, 256, 0, stream>>>(
            agg, ws_r + (size_t)r * IN_F * OUT_F, out, h_bias,
            r == 0, r == N_REL - 1);
    }
}

// Round 3
// 1011.672 us; speedup vs baseline: 6.0242x; 1.3104x over previous
//
#include <hip/hip_runtime.h>

#define N_NODES  50000
#define NPAD     50048          // 782 * 64
#define IN_F     128
#define OUT_F    128
#define N_REL    8
#define N_BASES  4
#define N_EDGES  800000
#define CAP      64             // Poisson(16): P(deg>64) ~ 1e-17, safe

typedef unsigned short ushort_t;
typedef __attribute__((ext_vector_type(8))) short short8;
typedef __attribute__((ext_vector_type(4))) float f32x4;

__device__ inline ushort_t f2bf(float f) {
    unsigned u = __float_as_uint(f);
    return (ushort_t)((u + 0x7fffu + ((u >> 16) & 1u)) >> 16);   // RNE
}

// BT[o][r*128+i] = sum_b w_comp[r,b]*weight[b,i,o]  (bf16, transposed for MFMA B-frag)
__global__ __launch_bounds__(256) void compute_ws_bt_kernel(
    const float* __restrict__ weight,
    const float* __restrict__ w_comp,
    ushort_t* __restrict__ BT)
{
    int idx = blockIdx.x * 256 + threadIdx.x;        // over 128*1024
    if (idx >= OUT_F * N_REL * IN_F) return;
    int o  = idx >> 10;
    int ri = idx & 1023;
    int r  = ri >> 7;
    int i  = ri & 127;
    float acc = 0.f;
#pragma unroll
    for (int b = 0; b < N_BASES; ++b)
        acc += w_comp[r * N_BASES + b] * weight[b * (IN_F * OUT_F) + i * OUT_F + o];
    BT[idx] = f2bf(acc);
}

// Per edge: count dst degree, drop src id into dst's bucket. r derived from flat index.
__global__ __launch_bounds__(256) void bucket_fill_kernel(
    const int* __restrict__ src,
    const int* __restrict__ dst,
    int* __restrict__ cnt,
    ushort_t* __restrict__ bucket,
    int nedges)
{
    int e = blockIdx.x * 256 + threadIdx.x;
    if (e >= nedges) return;
    int r = e / N_EDGES;                              // magic-mul (const divisor)
    int slot = r * N_NODES + dst[e];
    int pos = atomicAdd(&cnt[slot], 1);
    if (pos < CAP)
        bucket[(size_t)slot * CAP + pos] = (ushort_t)src[e];
}

// One wave per (relation, node): gather x rows via shfl-broadcast src ids,
// mean in f32, write 128 bf16 (one dword per lane, coalesced).
__global__ __launch_bounds__(256) void gather_mean_kernel(
    const float* __restrict__ x,
    const int* __restrict__ cnt,
    const ushort_t* __restrict__ bucket,
    ushort_t* __restrict__ A,
    int lda,                    // 1024 fused, 128 per-relation
    int total_waves)            // nR * N_NODES
{
    int wv = (blockIdx.x * 256 + threadIdx.x) >> 6;
    if (wv >= total_waves) return;
    int lane = threadIdx.x & 63;
    int r = wv / N_NODES;
    int n = wv - r * N_NODES;

    int c  = cnt[wv];
    int cc = min(c, CAP);
    int sid = (lane < cc) ? (int)bucket[(size_t)wv * CAP + lane] : 0;

    float ax = 0.f, ay = 0.f, bx = 0.f, by = 0.f;
    int e = 0;
    for (; e + 2 <= cc; e += 2) {
        int s0 = __shfl(sid, e);
        int s1 = __shfl(sid, e + 1);
        const float2 v0 = *(const float2*)(x + (size_t)s0 * IN_F + lane * 2);
        const float2 v1 = *(const float2*)(x + (size_t)s1 * IN_F + lane * 2);
        ax += v0.x; ay += v0.y;
        bx += v1.x; by += v1.y;
    }
    if (e < cc) {
        int s0 = __shfl(sid, e);
        const float2 v0 = *(const float2*)(x + (size_t)s0 * IN_F + lane * 2);
        ax += v0.x; ay += v0.y;
    }
    const float inv = 1.0f / fmaxf((float)c, 1.0f);
    unsigned lo = f2bf((ax + bx) * inv);
    unsigned hi = f2bf((ay + by) * inv);
    *(unsigned*)(A + (size_t)n * lda + r * IN_F + lane * 2) = lo | (hi << 16);
}

// C[NPAD x 128] (+)= A[NPAD x K]_bf16 @ B[K x 128]_bf16 (BT stored [128][1024]).
// Block 256 = 4 waves; block tile 64 rows x 128 cols; wave = 32 rows x 64 cols.
__global__ __launch_bounds__(256) void gemm_mfma_kernel(
    const ushort_t* __restrict__ A, int lda,
    const ushort_t* __restrict__ BT, int kbase, int K,
    float* __restrict__ out, const float* __restrict__ bias,
    int first, int last)
{
    int tid  = threadIdx.x;
    int wave = tid >> 6, lane = tid & 63;
    int rowf = lane & 15, kg = lane >> 4;           // A/B frag: row/col = lane&15, k-grp = lane>>4
    int rbase = blockIdx.x * 64 + (wave & 1) * 32;
    int cbase = (wave >> 1) * 64;

    f32x4 acc[2][4];
#pragma unroll
    for (int t = 0; t < 2; ++t)
#pragma unroll
        for (int c = 0; c < 4; ++c) acc[t][c] = (f32x4){0.f, 0.f, 0.f, 0.f};

    const ushort_t* Arow0 = A + (size_t)(rbase + rowf) * lda;
    const ushort_t* Arow1 = A + (size_t)(rbase + 16 + rowf) * lda;
    const ushort_t* Bbase = BT + (size_t)(cbase + rowf) * (N_REL * IN_F) + kbase;

    for (int k0 = 0; k0 < K; k0 += 32) {
        int kk = k0 + kg * 8;
        short8 a0 = *(const short8*)(Arow0 + kk);
        short8 a1 = *(const short8*)(Arow1 + kk);
#pragma unroll
        for (int c = 0; c < 4; ++c) {
            short8 b = *(const short8*)(Bbase + c * 16 * (N_REL * IN_F) + kk);
            acc[0][c] = __builtin_amdgcn_mfma_f32_16x16x32_bf16(a0, b, acc[0][c], 0, 0, 0);
            acc[1][c] = __builtin_amdgcn_mfma_f32_16x16x32_bf16(a1, b, acc[1][c], 0, 0, 0);
        }
    }

    // C/D layout: col = lane&15, row = (lane>>4)*4 + j   [m89-verified]
#pragma unroll
    for (int t = 0; t < 2; ++t) {
#pragma unroll
        for (int c = 0; c < 4; ++c) {
            int col = cbase + c * 16 + rowf;
#pragma unroll
            for (int j = 0; j < 4; ++j) {
                int row = rbase + t * 16 + kg * 4 + j;
                if (row < N_NODES) {
                    float v = acc[t][c][j];
                    float* p = out + (size_t)row * OUT_F + col;
                    if (!first) v += *p;
                    if (last)  v = fmaxf(v + bias[col], 0.f);
                    *p = v;
                }
            }
        }
    }
}

extern "C" void kernel_launch(void* const* d_in, const int* in_sizes, int n_in,
                              void* d_out, int out_size, void* d_ws, size_t ws_size,
                              hipStream_t stream) {
    const float* x      = (const float*)d_in[0];
    const float* weight = (const float*)d_in[1];
    const float* w_comp = (const float*)d_in[2];
    const float* h_bias = (const float*)d_in[3];
    const int*   src    = (const int*)d_in[4];
    const int*   dst    = (const int*)d_in[5];
    float* out = (float*)d_out;

    char* wsb = (char*)d_ws;
    ushort_t* BT = (ushort_t*)wsb;                        // 256 KB bf16 [128][1024]
    const size_t btSz = (size_t)OUT_F * N_REL * IN_F * 2; // 262144

    const size_t cntSzF = (size_t)N_REL * N_NODES * 4;          // 1.6 MB
    const size_t bktSzF = (size_t)N_REL * N_NODES * CAP * 2;    // 51.2 MB
    const size_t aSzF   = (size_t)NPAD * (N_REL * IN_F) * 2;    // 102.5 MB
    const size_t needF  = btSz + cntSzF + bktSzF + aSzF;        // ~155.6 MB

    compute_ws_bt_kernel<<<(OUT_F * N_REL * IN_F + 255) / 256, 256, 0, stream>>>(
        weight, w_comp, BT);

    if (ws_size >= needF) {
        // ---- fused path: all relations batched, one MFMA GEMM ----
        int*      cnt    = (int*)(wsb + btSz);
        ushort_t* bucket = (ushort_t*)(wsb + btSz + cntSzF);
        ushort_t* A      = (ushort_t*)(wsb + btSz + cntSzF + bktSzF);

        hipMemsetAsync(cnt, 0, cntSzF, stream);
        bucket_fill_kernel<<<(N_REL * N_EDGES + 255) / 256, 256, 0, stream>>>(
            src, dst, cnt, bucket, N_REL * N_EDGES);
        gather_mean_kernel<<<(N_REL * N_NODES * 64 + 255) / 256, 256, 0, stream>>>(
            x, cnt, bucket, A, N_REL * IN_F, N_REL * N_NODES);
        gemm_mfma_kernel<<<NPAD / 64, 256, 0, stream>>>(
            A, N_REL * IN_F, BT, 0, N_REL * IN_F, out, h_bias, 1, 1);
    } else {
        // ---- fallback: per-relation loop, small workspace (~19.7 MB) ----
        const size_t cntSz1 = (size_t)N_NODES * 4;
        const size_t bktSz1 = (size_t)N_NODES * CAP * 2;
        int*      cnt    = (int*)(wsb + btSz);
        ushort_t* bucket = (ushort_t*)(wsb + btSz + cntSz1);
        ushort_t* A      = (ushort_t*)(wsb + btSz + cntSz1 + bktSz1);

        for (int r = 0; r < N_REL; ++r) {
            hipMemsetAsync(cnt, 0, cntSz1, stream);
            bucket_fill_kernel<<<(N_EDGES + 255) / 256, 256, 0, stream>>>(
                src + (size_t)r * N_EDGES, dst + (size_t)r * N_EDGES,
                cnt, bucket, N_EDGES);
            gather_mean_kernel<<<(N_NODES * 64 + 255) / 256, 256, 0, stream>>>(
                x, cnt, bucket, A, IN_F, N_NODES);
            gemm_mfma_kernel<<<NPAD / 64, 256, 0, stream>>>(
                A, IN_F, BT, r * IN_F, IN_F, out, h_bias,
                r == 0, r == N_REL - 1);
        }
    }
}

// Round 4
// 878.834 us; speedup vs baseline: 6.9347x; 1.1512x over previous
//
#include <hip/hip_runtime.h>

#define N_NODES  50000
#define NPAD     50048          // 782 * 64
#define IN_F     128
#define OUT_F    128
#define N_REL    8
#define N_BASES  4
#define N_EDGES  800000
#define E4       (N_EDGES / 4)  // 200000
#define CAP      64             // Poisson(16): P(deg>64) ~ 1e-17
#define KTOT     (N_REL * IN_F) // 1024

typedef unsigned short ushort_t;
typedef __attribute__((ext_vector_type(8))) short short8;
typedef __attribute__((ext_vector_type(4))) float f32x4;

__device__ inline ushort_t f2bf(float f) {
    unsigned u = __float_as_uint(f);
    return (ushort_t)((u + 0x7fffu + ((u >> 16) & 1u)) >> 16);   // RNE
}
__device__ inline float bflo(unsigned v) { return __uint_as_float(v << 16); }
__device__ inline float bfhi(unsigned v) { return __uint_as_float(v & 0xffff0000u); }

// BT[o][r*128+i] = sum_b w_comp[r,b]*weight[b,i,o]  (bf16, B^T layout for MFMA)
__global__ __launch_bounds__(256) void compute_ws_bt_kernel(
    const float* __restrict__ weight,
    const float* __restrict__ w_comp,
    ushort_t* __restrict__ BT)
{
    int idx = blockIdx.x * 256 + threadIdx.x;        // over 128*1024
    if (idx >= OUT_F * KTOT) return;
    int o  = idx >> 10;
    int ri = idx & 1023;
    int r  = ri >> 7;
    int i  = ri & 127;
    float acc = 0.f;
#pragma unroll
    for (int b = 0; b < N_BASES; ++b)
        acc += w_comp[r * N_BASES + b] * weight[b * (IN_F * OUT_F) + i * OUT_F + o];
    BT[idx] = f2bf(acc);
}

// x (f32) -> xb (bf16), 4 elements/thread
__global__ __launch_bounds__(256) void x2bf_kernel(
    const float4* __restrict__ x4, uint2* __restrict__ xb)
{
    int i = blockIdx.x * 256 + threadIdx.x;
    if (i >= N_NODES * IN_F / 4) return;
    float4 v = x4[i];
    uint2 p;
    p.x = (unsigned)f2bf(v.x) | ((unsigned)f2bf(v.y) << 16);
    p.y = (unsigned)f2bf(v.z) | ((unsigned)f2bf(v.w) << 16);
    xb[i] = p;
}

// XCD-sharded fill: block (bid&7) handles relation (bid&7) only, so each
// XCD's bucket region (6.4 MB footprint, ~3 MB hot) stays in its own L2.
__global__ __launch_bounds__(256) void bucket_fill_shard_kernel(
    const int4* __restrict__ src4,
    const int4* __restrict__ dst4,
    int* __restrict__ cnt,
    ushort_t* __restrict__ bucket)
{
    int r  = blockIdx.x & 7;
    int cb = blockIdx.x >> 3;                         // 0..255
    const int4* s4 = src4 + (size_t)r * E4;
    const int4* d4 = dst4 + (size_t)r * E4;
    int slot0 = r * N_NODES;
    for (int i4 = cb * 256 + (int)threadIdx.x; i4 < E4; i4 += 256 * 256) {
        int4 s = s4[i4];
        int4 d = d4[i4];
#define PUT(DV, SV) { int sl = slot0 + (DV);                                  \
        int pos = atomicAdd(&cnt[sl], 1);                                     \
        if (pos < CAP) bucket[(size_t)sl * CAP + pos] = (ushort_t)(SV); }
        PUT(d.x, s.x) PUT(d.y, s.y) PUT(d.z, s.z) PUT(d.w, s.w)
#undef PUT
    }
}

// Fallback (unsharded) fill for small-workspace path.
__global__ __launch_bounds__(256) void bucket_fill_kernel(
    const int* __restrict__ src,
    const int* __restrict__ dst,
    int* __restrict__ cnt,
    ushort_t* __restrict__ bucket,
    int nedges)
{
    int e = blockIdx.x * 256 + threadIdx.x;
    if (e >= nedges) return;
    int d = dst[e];
    int pos = atomicAdd(&cnt[d], 1);
    if (pos < CAP)
        bucket[(size_t)d * CAP + pos] = (ushort_t)src[e];
}

// One wave per (relation, node), relation = bid&7 (same XCD that filled the
// bucket). Reads bf16 x rows (256B, 1 dword/lane), writes bf16 mean row.
__global__ __launch_bounds__(256) void gather_mean_bf_kernel(
    const unsigned* __restrict__ xb,   // [N][64] dwords
    const int* __restrict__ cnt,
    const ushort_t* __restrict__ bucket,
    ushort_t* __restrict__ A)          // [NPAD][1024]
{
    int r = blockIdx.x & 7;
    int n = (blockIdx.x >> 3) * 4 + ((int)threadIdx.x >> 6);
    int lane = threadIdx.x & 63;
    int slot = r * N_NODES + n;
    int c  = cnt[slot];
    int cc = min(c, CAP);
    int sid = (lane < cc) ? (int)bucket[(size_t)slot * CAP + lane] : 0;

    float ax = 0.f, ay = 0.f, bx = 0.f, by = 0.f;
    int e = 0;
    for (; e + 2 <= cc; e += 2) {
        int s0 = __shfl(sid, e);
        int s1 = __shfl(sid, e + 1);
        unsigned v0 = xb[(size_t)s0 * 64 + lane];
        unsigned v1 = xb[(size_t)s1 * 64 + lane];
        ax += bflo(v0); ay += bfhi(v0);
        bx += bflo(v1); by += bfhi(v1);
    }
    if (e < cc) {
        int s0 = __shfl(sid, e);
        unsigned v0 = xb[(size_t)s0 * 64 + lane];
        ax += bflo(v0); ay += bfhi(v0);
    }
    const float inv = 1.0f / fmaxf((float)c, 1.0f);
    unsigned lo = f2bf((ax + bx) * inv);
    unsigned hi = f2bf((ay + by) * inv);
    ((unsigned*)(A + (size_t)n * KTOT + r * IN_F))[lane] = lo | (hi << 16);
}

// Fallback gather (f32 x), per-relation A [NPAD][128].
__global__ __launch_bounds__(256) void gather_mean_fb_kernel(
    const float* __restrict__ x,
    const int* __restrict__ cnt,
    const ushort_t* __restrict__ bucket,
    ushort_t* __restrict__ A)
{
    int wv = (blockIdx.x * 256 + threadIdx.x) >> 6;
    if (wv >= N_NODES) return;
    int lane = threadIdx.x & 63;
    int c  = cnt[wv];
    int cc = min(c, CAP);
    int sid = (lane < cc) ? (int)bucket[(size_t)wv * CAP + lane] : 0;

    float ax = 0.f, ay = 0.f, bx = 0.f, by = 0.f;
    int e = 0;
    for (; e + 2 <= cc; e += 2) {
        int s0 = __shfl(sid, e);
        int s1 = __shfl(sid, e + 1);
        const float2 v0 = *(const float2*)(x + (size_t)s0 * IN_F + lane * 2);
        const float2 v1 = *(const float2*)(x + (size_t)s1 * IN_F + lane * 2);
        ax += v0.x; ay += v0.y;
        bx += v1.x; by += v1.y;
    }
    if (e < cc) {
        int s0 = __shfl(sid, e);
        const float2 v0 = *(const float2*)(x + (size_t)s0 * IN_F + lane * 2);
        ax += v0.x; ay += v0.y;
    }
    const float inv = 1.0f / fmaxf((float)c, 1.0f);
    unsigned lo = f2bf((ax + bx) * inv);
    unsigned hi = f2bf((ay + by) * inv);
    ((unsigned*)(A + (size_t)wv * IN_F))[lane] = lo | (hi << 16);
}

// C[rows x 128] (+)= A[rows x K]_bf16 @ B (BT stored [128][KTOT]).
// Block 256 = 4 waves; block tile 64 rows x 128 cols; wave = 32 rows x 64 cols.
__global__ __launch_bounds__(256) void gemm_mfma_kernel(
    const ushort_t* __restrict__ A, int lda,
    const ushort_t* __restrict__ BT, int kbase, int K,
    float* __restrict__ out, const float* __restrict__ bias,
    int first, int last)
{
    int tid  = threadIdx.x;
    int wave = tid >> 6, lane = tid & 63;
    int rowf = lane & 15, kg = lane >> 4;
    int rbase = blockIdx.x * 64 + (wave & 1) * 32;
    int cbase = (wave >> 1) * 64;

    f32x4 acc[2][4];
#pragma unroll
    for (int t = 0; t < 2; ++t)
#pragma unroll
        for (int c = 0; c < 4; ++c) acc[t][c] = (f32x4){0.f, 0.f, 0.f, 0.f};

    const ushort_t* Arow0 = A + (size_t)(rbase + rowf) * lda;
    const ushort_t* Arow1 = A + (size_t)(rbase + 16 + rowf) * lda;
    const ushort_t* Bbase = BT + (size_t)(cbase + rowf) * KTOT + kbase;

    for (int k0 = 0; k0 < K; k0 += 32) {
        int kk = k0 + kg * 8;
        short8 a0 = *(const short8*)(Arow0 + kk);
        short8 a1 = *(const short8*)(Arow1 + kk);
#pragma unroll
        for (int c = 0; c < 4; ++c) {
            short8 b = *(const short8*)(Bbase + c * 16 * KTOT + kk);
            acc[0][c] = __builtin_amdgcn_mfma_f32_16x16x32_bf16(a0, b, acc[0][c], 0, 0, 0);
            acc[1][c] = __builtin_amdgcn_mfma_f32_16x16x32_bf16(a1, b, acc[1][c], 0, 0, 0);
        }
    }

    // C/D layout: col = lane&15, row = (lane>>4)*4 + j
#pragma unroll
    for (int t = 0; t < 2; ++t) {
#pragma unroll
        for (int c = 0; c < 4; ++c) {
            int col = cbase + c * 16 + rowf;
#pragma unroll
            for (int j = 0; j < 4; ++j) {
                int row = rbase + t * 16 + kg * 4 + j;
                if (row < N_NODES) {
                    float v = acc[t][c][j];
                    float* p = out + (size_t)row * OUT_F + col;
                    if (!first) v += *p;
                    if (last)  v = fmaxf(v + bias[col], 0.f);
                    *p = v;
                }
            }
        }
    }
}

extern "C" void kernel_launch(void* const* d_in, const int* in_sizes, int n_in,
                              void* d_out, int out_size, void* d_ws, size_t ws_size,
                              hipStream_t stream) {
    const float* x      = (const float*)d_in[0];
    const float* weight = (const float*)d_in[1];
    const float* w_comp = (const float*)d_in[2];
    const float* h_bias = (const float*)d_in[3];
    const int*   src    = (const int*)d_in[4];
    const int*   dst    = (const int*)d_in[5];
    float* out = (float*)d_out;

    char* wsb = (char*)d_ws;
    const size_t btSz  = (size_t)OUT_F * KTOT * 2;            // 262144
    const size_t cntSz = (size_t)N_REL * N_NODES * 4;         // 1.6 MB
    const size_t bktSz = (size_t)N_REL * N_NODES * CAP * 2;   // 51.2 MB
    const size_t aSz   = (size_t)NPAD * KTOT * 2;             // 102.5 MB
    const size_t xbSz  = (size_t)N_NODES * IN_F * 2;          // 12.8 MB
    const size_t need  = btSz + cntSz + bktSz + aSz + xbSz;   // ~168.4 MB

    ushort_t* BT = (ushort_t*)wsb;
    compute_ws_bt_kernel<<<(OUT_F * KTOT + 255) / 256, 256, 0, stream>>>(
        weight, w_comp, BT);

    if (ws_size >= need) {
        int*      cnt    = (int*)(wsb + btSz);
        ushort_t* bucket = (ushort_t*)(wsb + btSz + cntSz);
        ushort_t* A      = (ushort_t*)(wsb + btSz + cntSz + bktSz);
        unsigned* xb     = (unsigned*)(wsb + btSz + cntSz + bktSz + aSz);

        x2bf_kernel<<<(N_NODES * IN_F / 4 + 255) / 256, 256, 0, stream>>>(
            (const float4*)x, (uint2*)xb);
        hipMemsetAsync(cnt, 0, cntSz, stream);
        bucket_fill_shard_kernel<<<8 * 256, 256, 0, stream>>>(
            (const int4*)src, (const int4*)dst, cnt, bucket);
        gather_mean_bf_kernel<<<8 * (N_NODES / 4), 256, 0, stream>>>(
            xb, cnt, bucket, A);
        gemm_mfma_kernel<<<NPAD / 64, 256, 0, stream>>>(
            A, KTOT, BT, 0, KTOT, out, h_bias, 1, 1);
    } else {
        // per-relation fallback (~19.7 MB)
        const size_t cntSz1 = (size_t)N_NODES * 4;
        const size_t bktSz1 = (size_t)N_NODES * CAP * 2;
        int*      cnt    = (int*)(wsb + btSz);
        ushort_t* bucket = (ushort_t*)(wsb + btSz + cntSz1);
        ushort_t* A      = (ushort_t*)(wsb + btSz + cntSz1 + bktSz1);

        for (int r = 0; r < N_REL; ++r) {
            hipMemsetAsync(cnt, 0, cntSz1, stream);
            bucket_fill_kernel<<<(N_EDGES + 255) / 256, 256, 0, stream>>>(
                src + (size_t)r * N_EDGES, dst + (size_t)r * N_EDGES,
                cnt, bucket, N_EDGES);
            gather_mean_fb_kernel<<<(N_NODES * 64 + 255) / 256, 256, 0, stream>>>(
                x, cnt, bucket, A);
            gemm_mfma_kernel<<<NPAD / 64, 256, 0, stream>>>(
                A, IN_F, BT, r * IN_F, IN_F, out, h_bias,
                r == 0, r == N_REL - 1);
        }
    }
}